// Round 5
// baseline (254.739 us; speedup 1.0000x reference)
//
#include <hip/hip_runtime.h>
#include <stdint.h>

#define D 128
#define K_NEI 10
#define TILE_M 64   // fused-fallback tile

typedef __bf16 bf16x8 __attribute__((ext_vector_type(8)));
typedef float f32x4 __attribute__((ext_vector_type(4)));

__device__ __forceinline__ uint32_t f2bf(float f) {
    union { float f; uint32_t u; } v; v.f = f;
    uint32_t u = v.u;
    return (u + 0x7FFFu + ((u >> 16) & 1u)) >> 16;   // RNE
}
__device__ __forceinline__ float bf2f(uint32_t h) {
    union { uint32_t u; float f; } v; v.u = h << 16; return v.f;
}
__device__ __forceinline__ uint32_t pack2(float a, float b) {
    return f2bf(a) | (f2bf(b) << 16);
}
__device__ __forceinline__ bf16x8 u4_as_bf16x8(uint4 u) {
    union { uint4 u; bf16x8 b; } v; v.u = u; return v.b;
}
// HW bf16 conversion (compiler emits v_cvt_pk_bf16_f32 for pairs)
__device__ __forceinline__ uint2 cvt4(f32x4 v) {
    union { __bf16 b[4]; uint2 u; } o;
    o.b[0] = (__bf16)v[0]; o.b[1] = (__bf16)v[1];
    o.b[2] = (__bf16)v[2]; o.b[3] = (__bf16)v[3];
    return o.u;
}
__device__ __forceinline__ bf16x8 cvt8(f32x4 lo, f32x4 hi) {
    union { __bf16 b[8]; bf16x8 v; } o;
    o.b[0] = (__bf16)lo[0]; o.b[1] = (__bf16)lo[1];
    o.b[2] = (__bf16)lo[2]; o.b[3] = (__bf16)lo[3];
    o.b[4] = (__bf16)hi[0]; o.b[5] = (__bf16)hi[1];
    o.b[6] = (__bf16)hi[2]; o.b[7] = (__bf16)hi[3];
    return o.v;
}

// ============================================================================
// prep: one launch, three independent block ranges.
//   [0, nCvt)            : raw f32 -> rawb bf16 (coalesced stream, 8 elems/thr)
//   [nCvt, nCvt+32)      : W1,W2 [128][256] f32 -> bf16 same layout, 0.1
//                          neighbor-mean scale folded into k>=128 columns
//   [nCvt+32, nCvt+192)  : zero used-node flags + compaction counter
// ============================================================================
__global__ void prep(const float* __restrict__ raw, int nCvt,
                     const float* __restrict__ W1, const float* __restrict__ W2,
                     uint16_t* __restrict__ rawb,
                     uint16_t* __restrict__ W1c, uint16_t* __restrict__ W2c,
                     int* __restrict__ flags, int* __restrict__ counter, int N1)
{
    const int b = blockIdx.x;
    if (b < nCvt) {
        size_t t = (size_t)b * 256 + threadIdx.x;    // 8 elems each
        const float* s = raw + t * 8;
        f32x4 a = *(const f32x4*)s;
        f32x4 c = *(const f32x4*)(s + 4);
        uint2 lo = cvt4(a), hi = cvt4(c);
        uint4 o; o.x = lo.x; o.y = lo.y; o.z = hi.x; o.w = hi.y;
        *(uint4*)(rawb + t * 8) = o;
    } else if (b < nCvt + 32) {
        const int b2 = b - nCvt;
        const float* W = (b2 < 16) ? W1 : W2;
        uint16_t*    O = (b2 < 16) ? W1c : W2c;
        int t = (b2 & 15) * 256 + threadIdx.x;       // 0..4095, 8 elems each
        const float s = (t & 16) ? 0.1f : 1.0f;      // col block (t&31)*8 -> agg iff t&16
        const float* src = W + (size_t)t * 8;
        f32x4 a = *(const f32x4*)src * s;
        f32x4 c = *(const f32x4*)(src + 4) * s;
        uint2 lo = cvt4(a), hi = cvt4(c);
        uint4 o; o.x = lo.x; o.y = lo.y; o.z = hi.x; o.w = hi.y;
        *(uint4*)(O + (size_t)t * 8) = o;
    } else {
        const int b3 = b - nCvt - 32;                // 0..159
        if (b3 == 0 && threadIdx.x == 0) *counter = 0;
        for (int i = b3 * 256 + threadIdx.x; i < N1; i += 160 * 256)
            flags[i] = 0;
    }
}

// ============================================================================
// mark_used: flag every layer-1 node that layer 2 will actually read.
// ============================================================================
__global__ void mark_used(const int* __restrict__ map_batch,
                          const int* __restrict__ neigh1,
                          int* __restrict__ flags, int B)
{
    const int t = blockIdx.x * 256 + threadIdx.x;
    const int T = B + B * K_NEI;
    if (t >= T) return;
    const int idx = (t < B) ? map_batch[t] : neigh1[t - B];
    flags[idx] = 1;
}

// ============================================================================
// compact_used: unordered compaction of flagged ids (order irrelevant).
// ============================================================================
__global__ void compact_used(const int* __restrict__ flags,
                             int* __restrict__ list, int* __restrict__ counter, int N1)
{
    const int i = blockIdx.x * 256 + threadIdx.x;
    if (i < N1 && flags[i]) {
        int p = atomicAdd(counter, 1);
        list[p] = i;
    }
}

// ============================================================================
// sage_fused_b: out[g] = relu([src[self[g]] | sum_k src[neigh[g][k]]] @ Wc^T)
// bf16 source (rawb). 0.1 pre-folded into Wc k>=128 cols.
// 128-thr blocks = 2 independent waves; lane (r16,q) gathers exactly its MFMA
// B-fragment. Gather is KS-MAJOR: per k-slice, ALL 10 neighbor loads issued
// before any accumulate (10 cache lines in flight/wave, temps capped at 40
// VGPR) -- bf16 rows are 2 lines each (half the f32 request count).
// ============================================================================
template <bool OUT_F32, bool USE_LIST>
__global__ __launch_bounds__(128)
void sage_fused_b(const uint16_t* __restrict__ src,   // [*][128] bf16
                  const uint16_t* __restrict__ Wc,    // [128][256] bf16, folded
                  const int* __restrict__ self_idx,
                  const int* __restrict__ neigh_idx,
                  void* __restrict__ out_, int M,
                  const int* __restrict__ list,
                  const int* __restrict__ cnt_p)
{
    const int tid  = threadIdx.x;
    const int lane = tid & 63;
    const int r16  = lane & 15;
    const int q    = lane >> 4;
    const int base = blockIdx.x * 32 + (tid >> 6) * 16;

    int g;
    if (USE_LIST) {
        const int cnt = *cnt_p;
        if (base >= cnt) return;                 // whole-wave early exit
        int li = base + r16;
        if (li >= cnt) li = cnt - 1;             // boundary dup: same-value writes
        g = list[li];
    } else {
        g = base + r16;
        if (base >= M) return;
        if (g >= M) g = M - 1;
    }

    const int2* nrow2 = (const int2*)(neigh_idx + (size_t)g * K_NEI);
    int idx[K_NEI];
    #pragma unroll
    for (int k = 0; k < 5; ++k) {
        int2 p = nrow2[k];
        idx[2 * k] = p.x; idx[2 * k + 1] = p.y;
    }
    const int self = self_idx[g];

    // self fragment loads (issued first, consumed last)
    const uint16_t* srow = src + (size_t)self * D + q * 8;
    uint4 sv[4];
    #pragma unroll
    for (int ks = 0; ks < 4; ++ks) sv[ks] = *(const uint4*)(srow + ks * 32);

    // neighbor base pointers hoisted once
    const uint16_t* np[K_NEI];
    #pragma unroll
    for (int k = 0; k < K_NEI; ++k) np[k] = src + (size_t)idx[k] * D + q * 8;

    f32x4 agg[8];
    #pragma unroll
    for (int x = 0; x < 8; ++x) agg[x] = (f32x4){0.f, 0.f, 0.f, 0.f};

    #pragma unroll
    for (int ks = 0; ks < 4; ++ks) {
        uint4 v[K_NEI];                          // 10 loads in flight
        #pragma unroll
        for (int k = 0; k < K_NEI; ++k) v[k] = *(const uint4*)(np[k] + ks * 32);
        #pragma unroll
        for (int k = 0; k < K_NEI; ++k) {
            agg[2 * ks]     += (f32x4){bf2f(v[k].x & 0xFFFFu), bf2f(v[k].x >> 16),
                                       bf2f(v[k].y & 0xFFFFu), bf2f(v[k].y >> 16)};
            agg[2 * ks + 1] += (f32x4){bf2f(v[k].z & 0xFFFFu), bf2f(v[k].z >> 16),
                                       bf2f(v[k].w & 0xFFFFu), bf2f(v[k].w >> 16)};
        }
    }

    bf16x8 a[8];
    #pragma unroll
    for (int ks = 0; ks < 4; ++ks) {
        a[ks]     = u4_as_bf16x8(sv[ks]);
        a[4 + ks] = cvt8(agg[2 * ks], agg[2 * ks + 1]);   // 0.1 folded into Wc
    }

    f32x4 acc[8];
    #pragma unroll
    for (int nt = 0; nt < 8; ++nt) acc[nt] = (f32x4){0.f, 0.f, 0.f, 0.f};

    const uint16_t* wb = Wc + (size_t)r16 * 256 + q * 8;  // L2-hot 64KB
    #pragma unroll
    for (int nt = 0; nt < 8; ++nt)
        #pragma unroll
        for (int ks = 0; ks < 8; ++ks) {
            bf16x8 w = *(const bf16x8*)(wb + (size_t)nt * 16 * 256 + ks * 32);
            acc[nt] = __builtin_amdgcn_mfma_f32_16x16x32_bf16(w, a[ks], acc[nt], 0, 0, 0);
        }

    // lane stores node g, out-cols nt*16 + q*4 .. +3
    #pragma unroll
    for (int nt = 0; nt < 8; ++nt) {
        f32x4 v = acc[nt];
        v[0] = v[0] > 0.f ? v[0] : 0.f;
        v[1] = v[1] > 0.f ? v[1] : 0.f;
        v[2] = v[2] > 0.f ? v[2] : 0.f;
        v[3] = v[3] > 0.f ? v[3] : 0.f;
        const int col = nt * 16 + q * 4;
        if (OUT_F32)
            *(f32x4*)((float*)out_ + (size_t)g * D + col) = v;
        else
            *(uint2*)((uint16_t*)out_ + (size_t)g * D + col) = cvt4(v);
    }
}

// ============================================================================
// gather_agg2: C[i] = [ h1[self_idx[i]] | sum_k h1[neigh_idx[i][k]] ]
// (NO 0.1 -- folded into W2c.) bf16 source, 16 thr/node: the light 36-VGPR
// shape that measured 3.25 TB/s @62% occupancy in R2. 2048 waves for L2
// (vs 512 deeply-serial fused waves in R3/R4 -- the hidden ~100us dispatch).
// ============================================================================
__global__ void gather_agg2(const uint16_t* __restrict__ src,
                            const int* __restrict__ self_idx,
                            const int* __restrict__ neigh_idx,
                            uint16_t* __restrict__ C, int M)
{
    const int t = blockIdx.x * 256 + threadIdx.x;
    const int i = t >> 4;        // node
    const int j = t & 15;        // lane-within-node
    if (i >= M) return;

    const int2* nrow2 = (const int2*)(neigh_idx + (size_t)i * K_NEI);
    int idx[K_NEI];
    #pragma unroll
    for (int k = 0; k < 5; ++k) {
        int2 p = nrow2[k];
        idx[2 * k] = p.x; idx[2 * k + 1] = p.y;
    }
    const int self = self_idx[i];
    uint16_t* c = C + (size_t)i * 256;

    uint4 sv = *(const uint4*)(src + (size_t)self * D + j * 8);
    float s0=0,s1=0,s2=0,s3=0,s4=0,s5=0,s6=0,s7=0;
    #pragma unroll
    for (int k = 0; k < K_NEI; ++k) {
        uint4 v = *(const uint4*)(src + (size_t)idx[k] * D + j * 8);
        s0 += bf2f(v.x & 0xFFFFu); s1 += bf2f(v.x >> 16);
        s2 += bf2f(v.y & 0xFFFFu); s3 += bf2f(v.y >> 16);
        s4 += bf2f(v.z & 0xFFFFu); s5 += bf2f(v.z >> 16);
        s6 += bf2f(v.w & 0xFFFFu); s7 += bf2f(v.w >> 16);
    }
    *(uint4*)(c + j * 8) = sv;
    uint4 o;
    o.x = pack2(s0, s1); o.y = pack2(s2, s3);
    o.z = pack2(s4, s5); o.w = pack2(s6, s7);
    *(uint4*)(c + 128 + j * 8) = o;
}

// ============================================================================
// gemm_k256: out[M][128] = relu(A[M][256] @ Wc^T)  (proven in R2)
// W-stationary in registers; swapped-operand MFMA; grid-stride tiles.
// ============================================================================
template <bool OUT_F32>
__global__ __launch_bounds__(256)
void gemm_k256(const uint16_t* __restrict__ A,    // [M][256] bf16
               const uint16_t* __restrict__ Wc,   // [128][256] bf16
               void* __restrict__ out_, int M)
{
    const int tid  = threadIdx.x;
    const int wave = tid >> 6;
    const int lane = tid & 63;
    const int r16  = lane & 15;
    const int q    = lane >> 4;
    const int h    = wave & 1;                     // 64-col half of output

    const int nTiles = M >> 4;
    const int stride = gridDim.x * 2;              // 2 waves per tile
    int tile = blockIdx.x * 2 + (wave >> 1);
    if (tile >= nTiles) return;

    // W fragments: out-col m = h*64 + nt*16 + r16, k = ks*32 + q*8 + 0..7
    bf16x8 Wf[4][8];
    {
        const uint16_t* wb = Wc + (size_t)(h * 64 + r16) * 256 + q * 8;
        #pragma unroll
        for (int nt = 0; nt < 4; ++nt)
            #pragma unroll
            for (int ks = 0; ks < 8; ++ks)
                Wf[nt][ks] = *(const bf16x8*)(wb + nt * 16 * 256 + ks * 32);
    }

    uint4 preB[8];
    {
        const uint16_t* row = A + (size_t)(tile * 16 + r16) * 256 + q * 8;
        #pragma unroll
        for (int ks = 0; ks < 8; ++ks) preB[ks] = *(const uint4*)(row + ks * 32);
    }

    while (tile < nTiles) {
        const int nxt = tile + stride;

        bf16x8 a[8];
        #pragma unroll
        for (int ks = 0; ks < 8; ++ks) a[ks] = u4_as_bf16x8(preB[ks]);

        if (nxt < nTiles) {
            const uint16_t* row = A + (size_t)(nxt * 16 + r16) * 256 + q * 8;
            #pragma unroll
            for (int ks = 0; ks < 8; ++ks) preB[ks] = *(const uint4*)(row + ks * 32);
        }

        f32x4 acc[4];
        #pragma unroll
        for (int nt = 0; nt < 4; ++nt) acc[nt] = (f32x4){0.f,0.f,0.f,0.f};

        #pragma unroll
        for (int ks = 0; ks < 8; ++ks)
            #pragma unroll
            for (int nt = 0; nt < 4; ++nt)
                acc[nt] = __builtin_amdgcn_mfma_f32_16x16x32_bf16(Wf[nt][ks], a[ks], acc[nt], 0, 0, 0);

        const size_t row = (size_t)(tile * 16 + r16);
        const int col0 = h * 64 + q * 4;
        #pragma unroll
        for (int nt = 0; nt < 4; ++nt) {
            f32x4 v = acc[nt];
            v[0] = v[0] > 0.f ? v[0] : 0.f;
            v[1] = v[1] > 0.f ? v[1] : 0.f;
            v[2] = v[2] > 0.f ? v[2] : 0.f;
            v[3] = v[3] > 0.f ? v[3] : 0.f;
            if (OUT_F32)
                *(f32x4*)((float*)out_ + row * 128 + col0 + nt * 16) = v;
            else
                *(uint2*)((uint16_t*)out_ + row * 128 + col0 + nt * 16) = cvt4(v);
        }
        tile = nxt;
    }
}

// ============================================================================
// Fallback: R3 fused kernel (proven) — only if ws too small / shapes off.
// ============================================================================
template <bool FEATS_F32, bool OUT_F32>
__global__ void sage_layer(const void* __restrict__ feats_,
                           const float* __restrict__ W,
                           const int* __restrict__ self_idx,
                           const int* __restrict__ neigh_idx,
                           void* __restrict__ out_)
{
    __shared__ __align__(16) uint16_t Alds[TILE_M * 128];
    __shared__ __align__(16) uint16_t Wlds[128 * 128];

    const int tid  = threadIdx.x;
    const int wave = tid >> 6;
    const int lane = tid & 63;
    const int r16  = lane & 15;
    const int q    = lane >> 4;
    const int G    = blockIdx.x * TILE_M;

    const float*    feats_f = (const float*)feats_;
    const uint16_t* feats_b = (const uint16_t*)feats_;

    f32x4 acc[8];
    #pragma unroll
    for (int nt = 0; nt < 8; ++nt) acc[nt] = (f32x4){0.f, 0.f, 0.f, 0.f};

    for (int half = 0; half < 2; ++half) {
        #pragma unroll
        for (int it = 0; it < 8; ++it) {
            int t = it * 256 + tid;
            int j = t >> 4, c = t & 15;
            const float* src = W + (size_t)j * 256 + half * 128 + c * 8;
            f32x4 w0 = *(const f32x4*)(src);
            f32x4 w1 = *(const f32x4*)(src + 4);
            uint4 o;
            o.x = pack2(w0[0], w0[1]); o.y = pack2(w0[2], w0[3]);
            o.z = pack2(w1[0], w1[1]); o.w = pack2(w1[2], w1[3]);
            int cs = c ^ (j & 15);
            *(uint4*)(Wlds + j * 128 + cs * 8) = o;
        }
        if (half == 0) {
            #pragma unroll
            for (int it = 0; it < 4; ++it) {
                int t = it * 256 + tid;
                int n = t >> 4, c = t & 15;
                int node = self_idx[G + n];
                uint4 o;
                if (FEATS_F32) {
                    const float* src = feats_f + (size_t)node * D + c * 8;
                    f32x4 f0 = *(const f32x4*)(src);
                    f32x4 f1 = *(const f32x4*)(src + 4);
                    o.x = pack2(f0[0], f0[1]); o.y = pack2(f0[2], f0[3]);
                    o.z = pack2(f1[0], f1[1]); o.w = pack2(f1[2], f1[3]);
                } else {
                    o = *(const uint4*)(feats_b + (size_t)node * D + c * 8);
                }
                int cs = c ^ (n & 15);
                *(uint4*)(Alds + n * 128 + cs * 8) = o;
            }
        } else {
            #pragma unroll
            for (int it = 0; it < 4; ++it) {
                int t = it * 256 + tid;
                int n = t >> 4, c = t & 15;
                const int* nrow = neigh_idx + (size_t)(G + n) * K_NEI;
                float s0=0,s1=0,s2=0,s3=0,s4=0,s5=0,s6=0,s7=0;
                #pragma unroll
                for (int k = 0; k < K_NEI; ++k) {
                    if (FEATS_F32) {
                        const float* src = feats_f + (size_t)nrow[k] * D + c * 8;
                        f32x4 f0 = *(const f32x4*)(src);
                        f32x4 f1 = *(const f32x4*)(src + 4);
                        s0 += f0[0]; s1 += f0[1]; s2 += f0[2]; s3 += f0[3];
                        s4 += f1[0]; s5 += f1[1]; s6 += f1[2]; s7 += f1[3];
                    } else {
                        uint4 v = *(const uint4*)(feats_b + (size_t)nrow[k] * D + c * 8);
                        s0 += bf2f(v.x & 0xFFFFu); s1 += bf2f(v.x >> 16);
                        s2 += bf2f(v.y & 0xFFFFu); s3 += bf2f(v.y >> 16);
                        s4 += bf2f(v.z & 0xFFFFu); s5 += bf2f(v.z >> 16);
                        s6 += bf2f(v.w & 0xFFFFu); s7 += bf2f(v.w >> 16);
                    }
                }
                const float inv = 0.1f;
                uint4 o;
                o.x = pack2(s0 * inv, s1 * inv);
                o.y = pack2(s2 * inv, s3 * inv);
                o.z = pack2(s4 * inv, s5 * inv);
                o.w = pack2(s6 * inv, s7 * inv);
                int cs = c ^ (n & 15);
                *(uint4*)(Alds + n * 128 + cs * 8) = o;
            }
        }
        __syncthreads();

        #pragma unroll
        for (int ks = 0; ks < 4; ++ks) {
            int cidx = ks * 4 + q;
            bf16x8 a = *(const bf16x8*)(Alds + (wave * 16 + r16) * 128 + ((cidx ^ r16) * 8));
            bf16x8 b[8];
            #pragma unroll
            for (int nt = 0; nt < 8; ++nt) {
                int jj = nt * 16 + r16;
                b[nt] = *(const bf16x8*)(Wlds + jj * 128 + ((cidx ^ r16) * 8));
            }
            #pragma unroll
            for (int nt = 0; nt < 8; ++nt)
                acc[nt] = __builtin_amdgcn_mfma_f32_16x16x32_bf16(a, b[nt], acc[nt], 0, 0, 0);
        }
        __syncthreads();
    }

    const int row_base = G + wave * 16 + q * 4;
    #pragma unroll
    for (int nt = 0; nt < 8; ++nt) {
        int col = nt * 16 + r16;
        #pragma unroll
        for (int r = 0; r < 4; ++r) {
            float v = acc[nt][r];
            v = v > 0.f ? v : 0.f;
            if (OUT_F32) ((float*)out_)[(size_t)(row_base + r) * D + col] = v;
            else ((uint16_t*)out_)[(size_t)(row_base + r) * D + col] = (uint16_t)f2bf(v);
        }
    }
}

extern "C" void kernel_launch(void* const* d_in, const int* in_sizes, int n_in,
                              void* d_out, int out_size, void* d_ws, size_t ws_size,
                              hipStream_t stream) {
    const float* raw = (const float*)d_in[0];          // [200000][128] fp32
    const float* W1  = (const float*)d_in[1];          // [128][256] fp32
    const float* W2  = (const float*)d_in[2];          // [128][256] fp32
    const int* layer1_nodes = (const int*)d_in[3];     // [81920]
    const int* neigh0       = (const int*)d_in[4];     // [81920][10]
    const int* map_batch    = (const int*)d_in[5];     // [8192]
    const int* neigh1       = (const int*)d_in[6];     // [8192][10]

    const int N_NODES = in_sizes[0] / D;   // 200000
    const int N1 = in_sizes[3];            // 81920
    const int B  = in_sizes[5];            // 8192

    const size_t szRawb = (size_t)N_NODES * 128 * 2;   // 51.2 MB
    const size_t szH1   = (size_t)N1 * 128 * 2;        // 21.0 MB
    const size_t szC2   = (size_t)B * 256 * 2;         //  4.2 MB
    const size_t szW    = 128 * 256 * 2;               // 64 KB
    const size_t szAux  = (size_t)N1 * 4 * 2 + 64;     // flags + list + counter
    const size_t need = szRawb + szH1 + szC2 + 2 * szW + szAux;

    if (ws_size >= need && (N_NODES % 16) == 0 && (N1 % 16) == 0 && (B % 16) == 0) {
        uint16_t* rawb = (uint16_t*)d_ws;
        uint16_t* h1   = rawb + (size_t)N_NODES * 128;
        uint16_t* C2   = h1 + (size_t)N1 * 128;
        uint16_t* W1c  = C2 + (size_t)B * 256;
        uint16_t* W2c  = W1c + 128 * 256;
        int*      flags   = (int*)(W2c + 128 * 256);
        int*      list    = flags + N1;
        int*      counter = list + N1;

        // One prep launch: raw->bf16 stream + W convert(+0.1 fold) + flag zeroing.
        const int nCvt = (N_NODES * D) / 2048;         // 12500
        prep<<<nCvt + 192, 256, 0, stream>>>(raw, nCvt, W1, W2, rawb, W1c, W2c,
                                             flags, counter, N1);

        // Flag + compact the ~67% of layer-1 nodes layer 2 actually reads.
        mark_used<<<(B + B * K_NEI + 255) / 256, 256, 0, stream>>>(map_batch, neigh1, flags, B);
        compact_used<<<(N1 + 255) / 256, 256, 0, stream>>>(flags, list, counter, N1);

        // Layer 1: fused gather+mean+GEMM over used nodes, bf16 source
        // (half the lines/req of f32; 51MB array L3-resident).
        sage_fused_b<false, true><<<(N1 + 31) / 32, 128, 0, stream>>>(
            rawb, W1c, layer1_nodes, neigh0, h1, N1, list, counter);

        // Layer 2 UNFUSED: light high-parallelism gather (2048 waves) + tiny GEMM.
        gather_agg2<<<(B * 16 + 255) / 256, 256, 0, stream>>>(h1, map_batch, neigh1, C2, B);
        gemm_k256<true><<<(B / 16 + 1) / 2, 256, 0, stream>>>(C2, W2c, d_out, B);
        return;
    }

    // Fallback: R3 fused path
    uint16_t* h1 = (uint16_t*)d_ws;
    sage_layer<true,  false><<<N1 / TILE_M, 256, 0, stream>>>(raw, W1, layer1_nodes, neigh0, h1);
    sage_layer<false, true ><<<B  / TILE_M, 256, 0, stream>>>(h1,  W2, map_batch,    neigh1, d_out);
}

// Round 6
// 232.642 us; speedup vs baseline: 1.0950x; 1.0950x over previous
//
#include <hip/hip_runtime.h>
#include <stdint.h>

#define D 128
#define K_NEI 10
#define TILE_M 64   // fused-fallback tile

typedef __bf16 bf16x8 __attribute__((ext_vector_type(8)));
typedef float f32x4 __attribute__((ext_vector_type(4)));

__device__ __forceinline__ uint32_t f2bf(float f) {
    union { float f; uint32_t u; } v; v.f = f;
    uint32_t u = v.u;
    return (u + 0x7FFFu + ((u >> 16) & 1u)) >> 16;   // RNE
}
__device__ __forceinline__ float bf2f(uint32_t h) {
    union { uint32_t u; float f; } v; v.u = h << 16; return v.f;
}
__device__ __forceinline__ uint32_t pack2(float a, float b) {
    return f2bf(a) | (f2bf(b) << 16);
}
__device__ __forceinline__ bf16x8 u4_as_bf16x8(uint4 u) {
    union { uint4 u; bf16x8 b; } v; v.u = u; return v.b;
}
// HW bf16 conversion (compiler emits v_cvt_pk_bf16_f32 for pairs)
__device__ __forceinline__ uint2 cvt4(f32x4 v) {
    union { __bf16 b[4]; uint2 u; } o;
    o.b[0] = (__bf16)v[0]; o.b[1] = (__bf16)v[1];
    o.b[2] = (__bf16)v[2]; o.b[3] = (__bf16)v[3];
    return o.u;
}

// ============================================================================
// prep: one launch, three independent block ranges.
//   [0, nCvt)            : raw f32 -> rawb bf16 (coalesced stream)
//   [nCvt, nCvt+32)      : W1,W2 [128][256] f32 -> bf16 same layout, 0.1
//                          neighbor-mean scale folded into k>=128 columns
//   [nCvt+32, nCvt+192)  : zero used-node flags + compaction counter
// ============================================================================
__global__ void prep(const float* __restrict__ raw, int nCvt,
                     const float* __restrict__ W1, const float* __restrict__ W2,
                     uint16_t* __restrict__ rawb,
                     uint16_t* __restrict__ W1c, uint16_t* __restrict__ W2c,
                     int* __restrict__ flags, int* __restrict__ counter, int N1)
{
    const int b = blockIdx.x;
    if (b < nCvt) {
        size_t t = (size_t)b * 256 + threadIdx.x;    // 8 elems each
        const float* s = raw + t * 8;
        f32x4 a = *(const f32x4*)s;
        f32x4 c = *(const f32x4*)(s + 4);
        uint2 lo = cvt4(a), hi = cvt4(c);
        uint4 o; o.x = lo.x; o.y = lo.y; o.z = hi.x; o.w = hi.y;
        *(uint4*)(rawb + t * 8) = o;
    } else if (b < nCvt + 32) {
        const int b2 = b - nCvt;
        const float* W = (b2 < 16) ? W1 : W2;
        uint16_t*    O = (b2 < 16) ? W1c : W2c;
        int t = (b2 & 15) * 256 + threadIdx.x;       // 0..4095, 8 elems each
        const float s = (t & 16) ? 0.1f : 1.0f;      // col block (t&31)*8 -> agg iff t&16
        const float* src = W + (size_t)t * 8;
        f32x4 a = *(const f32x4*)src * s;
        f32x4 c = *(const f32x4*)(src + 4) * s;
        uint2 lo = cvt4(a), hi = cvt4(c);
        uint4 o; o.x = lo.x; o.y = lo.y; o.z = hi.x; o.w = hi.y;
        *(uint4*)(O + (size_t)t * 8) = o;
    } else {
        const int b3 = b - nCvt - 32;                // 0..159
        if (b3 == 0 && threadIdx.x == 0) *counter = 0;
        for (int i = b3 * 256 + threadIdx.x; i < N1; i += 160 * 256)
            flags[i] = 0;
    }
}

// ============================================================================
// mark_compact: dedup-insert every layer-1 node layer 2 will read.
// atomicExch 0->1 wins exactly once per node; list order irrelevant.
// ============================================================================
__global__ void mark_compact(const int* __restrict__ map_batch,
                             const int* __restrict__ neigh1,
                             int* __restrict__ flags,
                             int* __restrict__ list, int* __restrict__ counter, int B)
{
    const int t = blockIdx.x * 256 + threadIdx.x;
    const int T = B + B * K_NEI;
    if (t >= T) return;
    const int idx = (t < B) ? map_batch[t] : neigh1[t - B];
    if (atomicExch(&flags[idx], 1) == 0) {
        int p = atomicAdd(counter, 1);
        list[p] = idx;
    }
}

// ============================================================================
// sage_tile: one 256-thread block = one 16-node output tile.
//   Phase 1 (gather, 16 thr/node -- the R2 high-occupancy shape):
//     thread (n = tid>>4, j = tid&15) loads 16B col-slice j*8 of the self row
//     and of 10 neighbor rows (two 5-deep clauses), fp32-accumulates, and
//     writes [self | sum] into LDS C[16][256] bf16, 8-elt blocks XOR-swizzled
//     by node (cs = j^n) to kill the 512B-stride bank conflict on phase 2.
//   Phase 2 (MFMA, after one barrier): wave w computes out-cols w*32..w*32+31:
//     A-frags (node data) via 8 ds_read_b128 (swizzle-aware), W-frags L2-hot
//     from the native [128][256] layout, 16 MFMA, relu, 8B/16B stores.
//   Swapped-operand MFMA layout identical to the proven gemm_k256 (R2/R5).
//   0.1 mean scale pre-folded into Wc k>=128 cols. USE_LIST: dead-row elim.
// ============================================================================
template <bool OUT_F32, bool USE_LIST>
__global__ __launch_bounds__(256, 4)
void sage_tile(const uint16_t* __restrict__ src,    // [*][128] bf16
               const uint16_t* __restrict__ Wc,     // [128][256] bf16, folded
               const int* __restrict__ self_idx,
               const int* __restrict__ neigh_idx,
               void* __restrict__ out_, int M,
               const int* __restrict__ list,
               const int* __restrict__ cnt_p)
{
    __shared__ __align__(16) uint16_t Clds[16 * 256];   // 8 KB

    const int tid  = threadIdx.x;
    const int base = blockIdx.x * 16;
    const int cnt  = USE_LIST ? *cnt_p : M;
    if (base >= cnt) return;                            // uniform whole-block exit

    // ---------------- phase 1: gather (16 thr/node) ----------------
    {
        const int n = tid >> 4;                         // node-in-tile 0..15
        const int j = tid & 15;                         // 16B col slice
        int li = base + n; if (li >= cnt) li = cnt - 1; // dup rows: same-value writes
        const int g = USE_LIST ? list[li] : li;

        const int2* nrow2 = (const int2*)(neigh_idx + (size_t)g * K_NEI);
        int idx[K_NEI];
        #pragma unroll
        for (int k = 0; k < 5; ++k) {
            int2 p = nrow2[k];
            idx[2 * k] = p.x; idx[2 * k + 1] = p.y;
        }
        const int self = self_idx[g];

        uint4 sv = *(const uint4*)(src + (size_t)self * D + j * 8);

        f32x4 a0 = (f32x4){0.f, 0.f, 0.f, 0.f};
        f32x4 a1 = (f32x4){0.f, 0.f, 0.f, 0.f};
        #pragma unroll
        for (int h = 0; h < 2; ++h) {                   // two 5-deep load clauses
            uint4 v[5];
            #pragma unroll
            for (int k = 0; k < 5; ++k)
                v[k] = *(const uint4*)(src + (size_t)idx[h * 5 + k] * D + j * 8);
            #pragma unroll
            for (int k = 0; k < 5; ++k) {
                a0 += (f32x4){bf2f(v[k].x & 0xFFFFu), bf2f(v[k].x >> 16),
                              bf2f(v[k].y & 0xFFFFu), bf2f(v[k].y >> 16)};
                a1 += (f32x4){bf2f(v[k].z & 0xFFFFu), bf2f(v[k].z >> 16),
                              bf2f(v[k].w & 0xFFFFu), bf2f(v[k].w >> 16)};
            }
        }

        const int cs = j ^ n;                           // swizzled 8-elt block
        *(uint4*)(Clds + n * 256 + cs * 8) = sv;        // self half (blocks 0..15)
        uint2 lo = cvt4(a0), hi = cvt4(a1);
        uint4 o; o.x = lo.x; o.y = lo.y; o.z = hi.x; o.w = hi.y;
        *(uint4*)(Clds + n * 256 + (16 + cs) * 8) = o;  // agg half (blocks 16..31)
    }
    __syncthreads();

    // ---------------- phase 2: MFMA (4 waves x 32 out-cols) ----------------
    const int wave = tid >> 6;
    const int lane = tid & 63;
    const int r16  = lane & 15;
    const int q    = lane >> 4;

    // A-fragments: node r16, k = ks*32 + q*8 .. +7 (swizzle-aware ds_read_b128)
    bf16x8 a[8];
    #pragma unroll
    for (int ks = 0; ks < 8; ++ks) {
        const int c  = ks * 4 + q;                      // 8-elt block 0..31
        const int cs = ((c & 15) ^ r16) | (c & 16);
        a[ks] = *(const bf16x8*)(Clds + r16 * 256 + cs * 8);
    }

    // W-fragments (L2-hot 64KB) + 16 MFMA: out-col m = wave*32 + nt*16 + r16
    f32x4 acc[2];
    acc[0] = (f32x4){0.f, 0.f, 0.f, 0.f};
    acc[1] = (f32x4){0.f, 0.f, 0.f, 0.f};
    const uint16_t* wb = Wc + (size_t)(wave * 32 + r16) * 256 + q * 8;
    #pragma unroll
    for (int nt = 0; nt < 2; ++nt)
        #pragma unroll
        for (int ks = 0; ks < 8; ++ks) {
            bf16x8 w = *(const bf16x8*)(wb + (size_t)nt * 16 * 256 + ks * 32);
            acc[nt] = __builtin_amdgcn_mfma_f32_16x16x32_bf16(w, a[ks], acc[nt], 0, 0, 0);
        }

    // store: lane owns node r16, out-cols wave*32 + nt*16 + q*4 .. +3
    int li = base + r16; if (li >= cnt) li = cnt - 1;
    const int g = USE_LIST ? list[li] : li;
    #pragma unroll
    for (int nt = 0; nt < 2; ++nt) {
        f32x4 v = acc[nt];
        v[0] = v[0] > 0.f ? v[0] : 0.f;
        v[1] = v[1] > 0.f ? v[1] : 0.f;
        v[2] = v[2] > 0.f ? v[2] : 0.f;
        v[3] = v[3] > 0.f ? v[3] : 0.f;
        const int col = wave * 32 + nt * 16 + q * 4;
        if (OUT_F32)
            *(f32x4*)((float*)out_ + (size_t)g * D + col) = v;
        else
            *(uint2*)((uint16_t*)out_ + (size_t)g * D + col) = cvt4(v);
    }
}

// ============================================================================
// Fallback: R3 fused kernel (proven) — only if ws too small.
// ============================================================================
template <bool FEATS_F32, bool OUT_F32>
__global__ void sage_layer(const void* __restrict__ feats_,
                           const float* __restrict__ W,
                           const int* __restrict__ self_idx,
                           const int* __restrict__ neigh_idx,
                           void* __restrict__ out_)
{
    __shared__ __align__(16) uint16_t Alds[TILE_M * 128];
    __shared__ __align__(16) uint16_t Wlds[128 * 128];

    const int tid  = threadIdx.x;
    const int wave = tid >> 6;
    const int lane = tid & 63;
    const int r16  = lane & 15;
    const int q    = lane >> 4;
    const int G    = blockIdx.x * TILE_M;

    const float*    feats_f = (const float*)feats_;
    const uint16_t* feats_b = (const uint16_t*)feats_;

    f32x4 acc[8];
    #pragma unroll
    for (int nt = 0; nt < 8; ++nt) acc[nt] = (f32x4){0.f, 0.f, 0.f, 0.f};

    for (int half = 0; half < 2; ++half) {
        #pragma unroll
        for (int it = 0; it < 8; ++it) {
            int t = it * 256 + tid;
            int j = t >> 4, c = t & 15;
            const float* src = W + (size_t)j * 256 + half * 128 + c * 8;
            f32x4 w0 = *(const f32x4*)(src);
            f32x4 w1 = *(const f32x4*)(src + 4);
            uint4 o;
            o.x = pack2(w0[0], w0[1]); o.y = pack2(w0[2], w0[3]);
            o.z = pack2(w1[0], w1[1]); o.w = pack2(w1[2], w1[3]);
            int cs = c ^ (j & 15);
            *(uint4*)(Wlds + j * 128 + cs * 8) = o;
        }
        if (half == 0) {
            #pragma unroll
            for (int it = 0; it < 4; ++it) {
                int t = it * 256 + tid;
                int n = t >> 4, c = t & 15;
                int node = self_idx[G + n];
                uint4 o;
                if (FEATS_F32) {
                    const float* src = feats_f + (size_t)node * D + c * 8;
                    f32x4 f0 = *(const f32x4*)(src);
                    f32x4 f1 = *(const f32x4*)(src + 4);
                    o.x = pack2(f0[0], f0[1]); o.y = pack2(f0[2], f0[3]);
                    o.z = pack2(f1[0], f1[1]); o.w = pack2(f1[2], f1[3]);
                } else {
                    o = *(const uint4*)(feats_b + (size_t)node * D + c * 8);
                }
                int cs = c ^ (n & 15);
                *(uint4*)(Alds + n * 128 + cs * 8) = o;
            }
        } else {
            #pragma unroll
            for (int it = 0; it < 4; ++it) {
                int t = it * 256 + tid;
                int n = t >> 4, c = t & 15;
                const int* nrow = neigh_idx + (size_t)(G + n) * K_NEI;
                float s0=0,s1=0,s2=0,s3=0,s4=0,s5=0,s6=0,s7=0;
                #pragma unroll
                for (int k = 0; k < K_NEI; ++k) {
                    if (FEATS_F32) {
                        const float* src = feats_f + (size_t)nrow[k] * D + c * 8;
                        f32x4 f0 = *(const f32x4*)(src);
                        f32x4 f1 = *(const f32x4*)(src + 4);
                        s0 += f0[0]; s1 += f0[1]; s2 += f0[2]; s3 += f0[3];
                        s4 += f1[0]; s5 += f1[1]; s6 += f1[2]; s7 += f1[3];
                    } else {
                        uint4 v = *(const uint4*)(feats_b + (size_t)nrow[k] * D + c * 8);
                        s0 += bf2f(v.x & 0xFFFFu); s1 += bf2f(v.x >> 16);
                        s2 += bf2f(v.y & 0xFFFFu); s3 += bf2f(v.y >> 16);
                        s4 += bf2f(v.z & 0xFFFFu); s5 += bf2f(v.z >> 16);
                        s6 += bf2f(v.w & 0xFFFFu); s7 += bf2f(v.w >> 16);
                    }
                }
                const float inv = 0.1f;
                uint4 o;
                o.x = pack2(s0 * inv, s1 * inv);
                o.y = pack2(s2 * inv, s3 * inv);
                o.z = pack2(s4 * inv, s5 * inv);
                o.w = pack2(s6 * inv, s7 * inv);
                int cs = c ^ (n & 15);
                *(uint4*)(Alds + n * 128 + cs * 8) = o;
            }
        }
        __syncthreads();

        #pragma unroll
        for (int ks = 0; ks < 4; ++ks) {
            int cidx = ks * 4 + q;
            bf16x8 a = *(const bf16x8*)(Alds + (wave * 16 + r16) * 128 + ((cidx ^ r16) * 8));
            bf16x8 b[8];
            #pragma unroll
            for (int nt = 0; nt < 8; ++nt) {
                int jj = nt * 16 + r16;
                b[nt] = *(const bf16x8*)(Wlds + jj * 128 + ((cidx ^ r16) * 8));
            }
            #pragma unroll
            for (int nt = 0; nt < 8; ++nt)
                acc[nt] = __builtin_amdgcn_mfma_f32_16x16x32_bf16(a, b[nt], acc[nt], 0, 0, 0);
        }
        __syncthreads();
    }

    const int row_base = G + wave * 16 + q * 4;
    #pragma unroll
    for (int nt = 0; nt < 8; ++nt) {
        int col = nt * 16 + r16;
        #pragma unroll
        for (int r = 0; r < 4; ++r) {
            float v = acc[nt][r];
            v = v > 0.f ? v : 0.f;
            if (OUT_F32) ((float*)out_)[(size_t)(row_base + r) * D + col] = v;
            else ((uint16_t*)out_)[(size_t)(row_base + r) * D + col] = (uint16_t)f2bf(v);
        }
    }
}

extern "C" void kernel_launch(void* const* d_in, const int* in_sizes, int n_in,
                              void* d_out, int out_size, void* d_ws, size_t ws_size,
                              hipStream_t stream) {
    const float* raw = (const float*)d_in[0];          // [200000][128] fp32
    const float* W1  = (const float*)d_in[1];          // [128][256] fp32
    const float* W2  = (const float*)d_in[2];          // [128][256] fp32
    const int* layer1_nodes = (const int*)d_in[3];     // [81920]
    const int* neigh0       = (const int*)d_in[4];     // [81920][10]
    const int* map_batch    = (const int*)d_in[5];     // [8192]
    const int* neigh1       = (const int*)d_in[6];     // [8192][10]

    const int N_NODES = in_sizes[0] / D;   // 200000
    const int N1 = in_sizes[3];            // 81920
    const int B  = in_sizes[5];            // 8192

    const size_t szRawb = (size_t)N_NODES * 128 * 2;   // 51.2 MB
    const size_t szH1   = (size_t)N1 * 128 * 2;        // 21.0 MB
    const size_t szW    = 128 * 256 * 2;               // 64 KB
    const size_t szAux  = (size_t)N1 * 4 * 2 + 64;     // flags + list + counter
    const size_t need = szRawb + szH1 + 2 * szW + szAux;

    if (ws_size >= need && (N_NODES % 16) == 0) {
        uint16_t* rawb = (uint16_t*)d_ws;
        uint16_t* h1   = rawb + (size_t)N_NODES * 128;
        uint16_t* W1c  = h1 + (size_t)N1 * 128;
        uint16_t* W2c  = W1c + 128 * 256;
        int*      flags   = (int*)(W2c + 128 * 256);
        int*      list    = flags + N1;
        int*      counter = list + N1;

        // 1. prep: raw->bf16 stream + W convert(+0.1 fold) + flag/counter zero.
        const int nCvt = (N_NODES * D) / 2048;         // 12500
        prep<<<nCvt + 192, 256, 0, stream>>>(raw, nCvt, W1, W2, rawb, W1c, W2c,
                                             flags, counter, N1);

        // 2. mark+compact in ONE kernel (atomicExch dedup-insert).
        mark_compact<<<(B + B * K_NEI + 255) / 256, 256, 0, stream>>>(
            map_batch, neigh1, flags, list, counter, B);

        // 3. Layer 1: tile-cooperative gather(16thr/node)+MFMA, used nodes only.
        sage_tile<false, true ><<<(N1 + 15) / 16, 256, 0, stream>>>(
            rawb, W1c, layer1_nodes, neigh0, h1, N1, list, counter);

        // 4. Layer 2: same kernel shape, 16x the gather parallelism of the
        //    R4 fused-L2 (which measured 101us at 138 GB/s -- pure latency).
        sage_tile<true,  false><<<(B + 15) / 16, 256, 0, stream>>>(
            h1, W2c, map_batch, neigh1, d_out, B, nullptr, nullptr);
        return;
    }

    // Fallback: R3 fused path
    uint16_t* h1 = (uint16_t*)d_ws;
    sage_layer<true,  false><<<N1 / TILE_M, 256, 0, stream>>>(raw, W1, layer1_nodes, neigh0, h1);
    sage_layer<false, true ><<<B  / TILE_M, 256, 0, stream>>>(h1,  W2, map_batch,    neigh1, d_out);
}

// Round 7
// 230.285 us; speedup vs baseline: 1.1062x; 1.0102x over previous
//
#include <hip/hip_runtime.h>
#include <stdint.h>

#define D 128
#define K_NEI 10
#define TILE_M 64   // fused-fallback tile

typedef __bf16 bf16x8 __attribute__((ext_vector_type(8)));
typedef float f32x4 __attribute__((ext_vector_type(4)));

__device__ __forceinline__ uint32_t f2bf(float f) {
    union { float f; uint32_t u; } v; v.f = f;
    uint32_t u = v.u;
    return (u + 0x7FFFu + ((u >> 16) & 1u)) >> 16;   // RNE
}
__device__ __forceinline__ float bf2f(uint32_t h) {
    union { uint32_t u; float f; } v; v.u = h << 16; return v.f;
}
__device__ __forceinline__ uint32_t pack2(float a, float b) {
    return f2bf(a) | (f2bf(b) << 16);
}
__device__ __forceinline__ bf16x8 u4_as_bf16x8(uint4 u) {
    union { uint4 u; bf16x8 b; } v; v.u = u; return v.b;
}
// HW bf16 conversion (compiler emits v_cvt_pk_bf16_f32 for pairs)
__device__ __forceinline__ uint2 cvt4(f32x4 v) {
    union { __bf16 b[4]; uint2 u; } o;
    o.b[0] = (__bf16)v[0]; o.b[1] = (__bf16)v[1];
    o.b[2] = (__bf16)v[2]; o.b[3] = (__bf16)v[3];
    return o.u;
}

// ============================================================================
// prep: one launch, three independent block ranges.
//   [0, nCvt)            : raw f32 -> rawb bf16 (coalesced stream)
//   [nCvt, nCvt+32)      : W1,W2 [128][256] f32 -> bf16 same layout, 0.1
//                          neighbor-mean scale folded into k>=128 columns
//   [nCvt+32, nCvt+192)  : zero used-node flags + compaction counter
// ============================================================================
__global__ void prep(const float* __restrict__ raw, int nCvt,
                     const float* __restrict__ W1, const float* __restrict__ W2,
                     uint16_t* __restrict__ rawb,
                     uint16_t* __restrict__ W1c, uint16_t* __restrict__ W2c,
                     int* __restrict__ flags, int* __restrict__ counter, int N1)
{
    const int b = blockIdx.x;
    if (b < nCvt) {
        size_t t = (size_t)b * 256 + threadIdx.x;    // 8 elems each
        const float* s = raw + t * 8;
        f32x4 a = *(const f32x4*)s;
        f32x4 c = *(const f32x4*)(s + 4);
        uint2 lo = cvt4(a), hi = cvt4(c);
        uint4 o; o.x = lo.x; o.y = lo.y; o.z = hi.x; o.w = hi.y;
        *(uint4*)(rawb + t * 8) = o;
    } else if (b < nCvt + 32) {
        const int b2 = b - nCvt;
        const float* W = (b2 < 16) ? W1 : W2;
        uint16_t*    O = (b2 < 16) ? W1c : W2c;
        int t = (b2 & 15) * 256 + threadIdx.x;       // 0..4095, 8 elems each
        const float s = (t & 16) ? 0.1f : 1.0f;      // col block (t&31)*8 -> agg iff t&16
        const float* src = W + (size_t)t * 8;
        f32x4 a = *(const f32x4*)src * s;
        f32x4 c = *(const f32x4*)(src + 4) * s;
        uint2 lo = cvt4(a), hi = cvt4(c);
        uint4 o; o.x = lo.x; o.y = lo.y; o.z = hi.x; o.w = hi.y;
        *(uint4*)(O + (size_t)t * 8) = o;
    } else {
        const int b3 = b - nCvt - 32;                // 0..159
        if (b3 == 0 && threadIdx.x == 0) *counter = 0;
        for (int i = b3 * 256 + threadIdx.x; i < N1; i += 160 * 256)
            flags[i] = 0;
    }
}

// ============================================================================
// mark_compact: dedup-insert every layer-1 node layer 2 will read.
// atomicExch 0->1 wins exactly once per node; list order irrelevant.
// ============================================================================
__global__ void mark_compact(const int* __restrict__ map_batch,
                             const int* __restrict__ neigh1,
                             int* __restrict__ flags,
                             int* __restrict__ list, int* __restrict__ counter, int B)
{
    const int t = blockIdx.x * 256 + threadIdx.x;
    const int T = B + B * K_NEI;
    if (t >= T) return;
    const int idx = (t < B) ? map_batch[t] : neigh1[t - B];
    if (atomicExch(&flags[idx], 1) == 0) {
        int p = atomicAdd(counter, 1);
        list[p] = idx;
    }
}

// ============================================================================
// sage_tile: one 256-thread block = one (16*NPT)-node output tile.
//   NPT = nodes per thread (2 for L1: doubles per-wave load-clause depth,
//   the lever for a latency-bound gather at fixed occupancy; 1 for L2 to
//   keep its block count at 512 -- at NPT=2 L2 would drop to 1 block/CU).
//
//   Phase 1 (gather, 16 thr/node): thread (n0 = tid>>4, j = tid&15) owns
//     nodes n0 + s*16, loads 16B col-slice j of self + 10 neighbor rows
//     (interleaved 2x(5*NPT)-deep clauses -> 10 loads in flight at NPT=2),
//     fp32-accumulates, writes [self | sum] to LDS C[16*NPT][256] bf16 with
//     per-node XOR swizzle (cs = j ^ n0) -- 2-way bank alias, free (m136).
//   Phase 2 (MFMA, one barrier): wave w -> out-cols w*32..w*32+31. W-frags
//     loaded ONCE per (nt,ks) and reused across the NPT node groups (halves
//     W L2 traffic, 2x MFMA ILP). Swapped-operand MFMA (proven R2-R6):
//     lane = node r16 of its group, 4 consecutive out-cols per acc reg.
//   0.1 mean scale pre-folded into Wc k>=128 cols. USE_LIST: dead-row elim.
// ============================================================================
template <bool OUT_F32, bool USE_LIST, int NPT>
__global__ __launch_bounds__(256, 4)
void sage_tile(const uint16_t* __restrict__ src,    // [*][128] bf16
               const uint16_t* __restrict__ Wc,     // [128][256] bf16, folded
               const int* __restrict__ self_idx,
               const int* __restrict__ neigh_idx,
               void* __restrict__ out_, int M,
               const int* __restrict__ list,
               const int* __restrict__ cnt_p)
{
    __shared__ __align__(16) uint16_t Clds[16 * NPT * 256];   // 8/16 KB

    const int tid  = threadIdx.x;
    const int base = blockIdx.x * (16 * NPT);
    const int cnt  = USE_LIST ? *cnt_p : M;
    if (base >= cnt) return;                            // uniform whole-block exit

    // ---------------- phase 1: gather (16 thr/node, NPT nodes/thread) -------
    {
        const int n0 = tid >> 4;                        // node-in-group 0..15
        const int j  = tid & 15;                        // 16B col slice
        const int cs = j ^ n0;                          // swizzled 8-elt block

        int idx[NPT][K_NEI];
        const uint16_t* srow[NPT];
        #pragma unroll
        for (int s = 0; s < NPT; ++s) {
            int li = base + s * 16 + n0;
            if (li >= cnt) li = cnt - 1;                // dup rows: same-value writes
            const int g = USE_LIST ? list[li] : li;
            const int2* nrow2 = (const int2*)(neigh_idx + (size_t)g * K_NEI);
            #pragma unroll
            for (int k = 0; k < 5; ++k) {
                int2 p = nrow2[k];
                idx[s][2 * k] = p.x; idx[s][2 * k + 1] = p.y;
            }
            srow[s] = src + (size_t)self_idx[g] * D + j * 8;
        }

        uint4 sv[NPT];
        #pragma unroll
        for (int s = 0; s < NPT; ++s) sv[s] = *(const uint4*)srow[s];

        f32x4 a0[NPT], a1[NPT];
        #pragma unroll
        for (int s = 0; s < NPT; ++s) {
            a0[s] = (f32x4){0.f, 0.f, 0.f, 0.f};
            a1[s] = (f32x4){0.f, 0.f, 0.f, 0.f};
        }
        #pragma unroll
        for (int h = 0; h < 2; ++h) {                   // 2 clauses of 5*NPT loads
            uint4 v[NPT][5];
            #pragma unroll
            for (int s = 0; s < NPT; ++s)
                #pragma unroll
                for (int k = 0; k < 5; ++k)
                    v[s][k] = *(const uint4*)(src + (size_t)idx[s][h * 5 + k] * D + j * 8);
            #pragma unroll
            for (int s = 0; s < NPT; ++s)
                #pragma unroll
                for (int k = 0; k < 5; ++k) {
                    a0[s] += (f32x4){bf2f(v[s][k].x & 0xFFFFu), bf2f(v[s][k].x >> 16),
                                     bf2f(v[s][k].y & 0xFFFFu), bf2f(v[s][k].y >> 16)};
                    a1[s] += (f32x4){bf2f(v[s][k].z & 0xFFFFu), bf2f(v[s][k].z >> 16),
                                     bf2f(v[s][k].w & 0xFFFFu), bf2f(v[s][k].w >> 16)};
                }
        }

        #pragma unroll
        for (int s = 0; s < NPT; ++s) {
            const int row = s * 16 + n0;
            *(uint4*)(Clds + row * 256 + cs * 8) = sv[s];        // self (blocks 0..15)
            uint2 lo = cvt4(a0[s]), hi = cvt4(a1[s]);
            uint4 o; o.x = lo.x; o.y = lo.y; o.z = hi.x; o.w = hi.y;
            *(uint4*)(Clds + row * 256 + (16 + cs) * 8) = o;     // agg (blocks 16..31)
        }
    }
    __syncthreads();

    // ---------------- phase 2: MFMA (4 waves x 32 out-cols) -----------------
    const int wave = tid >> 6;
    const int lane = tid & 63;
    const int r16  = lane & 15;
    const int q    = lane >> 4;

    // A-fragments: node group s, row s*16+r16, k = ks*32 + q*8 .. +7
    bf16x8 a[NPT][8];
    #pragma unroll
    for (int s = 0; s < NPT; ++s)
        #pragma unroll
        for (int ks = 0; ks < 8; ++ks) {
            const int c  = ks * 4 + q;                  // 8-elt block 0..31
            const int cs = ((c & 15) ^ r16) | (c & 16);
            a[s][ks] = *(const bf16x8*)(Clds + (s * 16 + r16) * 256 + cs * 8);
        }

    // W loaded once per (nt,ks), reused across node groups.
    f32x4 acc[NPT][2];
    #pragma unroll
    for (int s = 0; s < NPT; ++s) {
        acc[s][0] = (f32x4){0.f, 0.f, 0.f, 0.f};
        acc[s][1] = (f32x4){0.f, 0.f, 0.f, 0.f};
    }
    const uint16_t* wb = Wc + (size_t)(wave * 32 + r16) * 256 + q * 8;
    #pragma unroll
    for (int nt = 0; nt < 2; ++nt)
        #pragma unroll
        for (int ks = 0; ks < 8; ++ks) {
            bf16x8 w = *(const bf16x8*)(wb + (size_t)nt * 16 * 256 + ks * 32);
            #pragma unroll
            for (int s = 0; s < NPT; ++s)
                acc[s][nt] = __builtin_amdgcn_mfma_f32_16x16x32_bf16(w, a[s][ks], acc[s][nt], 0, 0, 0);
        }

    // store: lane owns node (s*16 + r16), out-cols wave*32 + nt*16 + q*4 .. +3
    #pragma unroll
    for (int s = 0; s < NPT; ++s) {
        int li = base + s * 16 + r16;
        if (li >= cnt) li = cnt - 1;
        const int g = USE_LIST ? list[li] : li;
        #pragma unroll
        for (int nt = 0; nt < 2; ++nt) {
            f32x4 v = acc[s][nt];
            v[0] = v[0] > 0.f ? v[0] : 0.f;
            v[1] = v[1] > 0.f ? v[1] : 0.f;
            v[2] = v[2] > 0.f ? v[2] : 0.f;
            v[3] = v[3] > 0.f ? v[3] : 0.f;
            const int col = wave * 32 + nt * 16 + q * 4;
            if (OUT_F32)
                *(f32x4*)((float*)out_ + (size_t)g * D + col) = v;
            else
                *(uint2*)((uint16_t*)out_ + (size_t)g * D + col) = cvt4(v);
        }
    }
}

// ============================================================================
// Fallback: R3 fused kernel (proven) — only if ws too small.
// ============================================================================
template <bool FEATS_F32, bool OUT_F32>
__global__ void sage_layer(const void* __restrict__ feats_,
                           const float* __restrict__ W,
                           const int* __restrict__ self_idx,
                           const int* __restrict__ neigh_idx,
                           void* __restrict__ out_)
{
    __shared__ __align__(16) uint16_t Alds[TILE_M * 128];
    __shared__ __align__(16) uint16_t Wlds[128 * 128];

    const int tid  = threadIdx.x;
    const int wave = tid >> 6;
    const int lane = tid & 63;
    const int r16  = lane & 15;
    const int q    = lane >> 4;
    const int G    = blockIdx.x * TILE_M;

    const float*    feats_f = (const float*)feats_;
    const uint16_t* feats_b = (const uint16_t*)feats_;

    f32x4 acc[8];
    #pragma unroll
    for (int nt = 0; nt < 8; ++nt) acc[nt] = (f32x4){0.f, 0.f, 0.f, 0.f};

    for (int half = 0; half < 2; ++half) {
        #pragma unroll
        for (int it = 0; it < 8; ++it) {
            int t = it * 256 + tid;
            int j = t >> 4, c = t & 15;
            const float* src = W + (size_t)j * 256 + half * 128 + c * 8;
            f32x4 w0 = *(const f32x4*)(src);
            f32x4 w1 = *(const f32x4*)(src + 4);
            uint4 o;
            o.x = pack2(w0[0], w0[1]); o.y = pack2(w0[2], w0[3]);
            o.z = pack2(w1[0], w1[1]); o.w = pack2(w1[2], w1[3]);
            int cs = c ^ (j & 15);
            *(uint4*)(Wlds + j * 128 + cs * 8) = o;
        }
        if (half == 0) {
            #pragma unroll
            for (int it = 0; it < 4; ++it) {
                int t = it * 256 + tid;
                int n = t >> 4, c = t & 15;
                int node = self_idx[G + n];
                uint4 o;
                if (FEATS_F32) {
                    const float* src = feats_f + (size_t)node * D + c * 8;
                    f32x4 f0 = *(const f32x4*)(src);
                    f32x4 f1 = *(const f32x4*)(src + 4);
                    o.x = pack2(f0[0], f0[1]); o.y = pack2(f0[2], f0[3]);
                    o.z = pack2(f1[0], f1[1]); o.w = pack2(f1[2], f1[3]);
                } else {
                    o = *(const uint4*)(feats_b + (size_t)node * D + c * 8);
                }
                int cs = c ^ (n & 15);
                *(uint4*)(Alds + n * 128 + cs * 8) = o;
            }
        } else {
            #pragma unroll
            for (int it = 0; it < 4; ++it) {
                int t = it * 256 + tid;
                int n = t >> 4, c = t & 15;
                const int* nrow = neigh_idx + (size_t)(G + n) * K_NEI;
                float s0=0,s1=0,s2=0,s3=0,s4=0,s5=0,s6=0,s7=0;
                #pragma unroll
                for (int k = 0; k < K_NEI; ++k) {
                    if (FEATS_F32) {
                        const float* src = feats_f + (size_t)nrow[k] * D + c * 8;
                        f32x4 f0 = *(const f32x4*)(src);
                        f32x4 f1 = *(const f32x4*)(src + 4);
                        s0 += f0[0]; s1 += f0[1]; s2 += f0[2]; s3 += f0[3];
                        s4 += f1[0]; s5 += f1[1]; s6 += f1[2]; s7 += f1[3];
                    } else {
                        uint4 v = *(const uint4*)(feats_b + (size_t)nrow[k] * D + c * 8);
                        s0 += bf2f(v.x & 0xFFFFu); s1 += bf2f(v.x >> 16);
                        s2 += bf2f(v.y & 0xFFFFu); s3 += bf2f(v.y >> 16);
                        s4 += bf2f(v.z & 0xFFFFu); s5 += bf2f(v.z >> 16);
                        s6 += bf2f(v.w & 0xFFFFu); s7 += bf2f(v.w >> 16);
                    }
                }
                const float inv = 0.1f;
                uint4 o;
                o.x = pack2(s0 * inv, s1 * inv);
                o.y = pack2(s2 * inv, s3 * inv);
                o.z = pack2(s4 * inv, s5 * inv);
                o.w = pack2(s6 * inv, s7 * inv);
                int cs = c ^ (n & 15);
                *(uint4*)(Alds + n * 128 + cs * 8) = o;
            }
        }
        __syncthreads();

        #pragma unroll
        for (int ks = 0; ks < 4; ++ks) {
            int cidx = ks * 4 + q;
            bf16x8 a = *(const bf16x8*)(Alds + (wave * 16 + r16) * 128 + ((cidx ^ r16) * 8));
            bf16x8 b[8];
            #pragma unroll
            for (int nt = 0; nt < 8; ++nt) {
                int jj = nt * 16 + r16;
                b[nt] = *(const bf16x8*)(Wlds + jj * 128 + ((cidx ^ r16) * 8));
            }
            #pragma unroll
            for (int nt = 0; nt < 8; ++nt)
                acc[nt] = __builtin_amdgcn_mfma_f32_16x16x32_bf16(a, b[nt], acc[nt], 0, 0, 0);
        }
        __syncthreads();
    }

    const int row_base = G + wave * 16 + q * 4;
    #pragma unroll
    for (int nt = 0; nt < 8; ++nt) {
        int col = nt * 16 + r16;
        #pragma unroll
        for (int r = 0; r < 4; ++r) {
            float v = acc[nt][r];
            v = v > 0.f ? v : 0.f;
            if (OUT_F32) ((float*)out_)[(size_t)(row_base + r) * D + col] = v;
            else ((uint16_t*)out_)[(size_t)(row_base + r) * D + col] = (uint16_t)f2bf(v);
        }
    }
}

extern "C" void kernel_launch(void* const* d_in, const int* in_sizes, int n_in,
                              void* d_out, int out_size, void* d_ws, size_t ws_size,
                              hipStream_t stream) {
    const float* raw = (const float*)d_in[0];          // [200000][128] fp32
    const float* W1  = (const float*)d_in[1];          // [128][256] fp32
    const float* W2  = (const float*)d_in[2];          // [128][256] fp32
    const int* layer1_nodes = (const int*)d_in[3];     // [81920]
    const int* neigh0       = (const int*)d_in[4];     // [81920][10]
    const int* map_batch    = (const int*)d_in[5];     // [8192]
    const int* neigh1       = (const int*)d_in[6];     // [8192][10]

    const int N_NODES = in_sizes[0] / D;   // 200000
    const int N1 = in_sizes[3];            // 81920
    const int B  = in_sizes[5];            // 8192

    const size_t szRawb = (size_t)N_NODES * 128 * 2;   // 51.2 MB
    const size_t szH1   = (size_t)N1 * 128 * 2;        // 21.0 MB
    const size_t szW    = 128 * 256 * 2;               // 64 KB
    const size_t szAux  = (size_t)N1 * 4 * 2 + 64;     // flags + list + counter
    const size_t need = szRawb + szH1 + 2 * szW + szAux;

    if (ws_size >= need && (N_NODES % 16) == 0) {
        uint16_t* rawb = (uint16_t*)d_ws;
        uint16_t* h1   = rawb + (size_t)N_NODES * 128;
        uint16_t* W1c  = h1 + (size_t)N1 * 128;
        uint16_t* W2c  = W1c + 128 * 256;
        int*      flags   = (int*)(W2c + 128 * 256);
        int*      list    = flags + N1;
        int*      counter = list + N1;

        // 1. prep: raw->bf16 stream + W convert(+0.1 fold) + flag/counter zero.
        const int nCvt = (N_NODES * D) / 2048;         // 12500
        prep<<<nCvt + 192, 256, 0, stream>>>(raw, nCvt, W1, W2, rawb, W1c, W2c,
                                             flags, counter, N1);

        // 2. mark+compact in ONE kernel (atomicExch dedup-insert).
        mark_compact<<<(B + B * K_NEI + 255) / 256, 256, 0, stream>>>(
            map_batch, neigh1, flags, list, counter, B);

        // 3. Layer 1: 32-node tiles, 2 nodes/thread -> 10-deep gather clauses
        //    (2x in-flight loads/wave at unchanged occupancy), used nodes only.
        sage_tile<false, true,  2><<<(N1 + 31) / 32, 256, 0, stream>>>(
            rawb, W1c, layer1_nodes, neigh0, h1, N1, list, counter);

        // 4. Layer 2: 16-node tiles (keeps 512 blocks = 2/CU; NPT=2 would
        //    halve block count into the R4-L2 latency trap).
        sage_tile<true,  false, 1><<<(B + 15) / 16, 256, 0, stream>>>(
            h1, W2c, map_batch, neigh1, d_out, B, nullptr, nullptr);
        return;
    }

    // Fallback: R3 fused path
    uint16_t* h1 = (uint16_t*)d_ws;
    sage_layer<true,  false><<<N1 / TILE_M, 256, 0, stream>>>(raw, W1, layer1_nodes, neigh0, h1);
    sage_layer<false, true ><<<B  / TILE_M, 256, 0, stream>>>(h1,  W2, map_batch,    neigh1, d_out);
}